// Round 17
// baseline (167.004 us; speedup 1.0000x reference)
//
#include <hip/hip_runtime.h>

// EFN edge-MLP + scatter-add, MI355X (gfx950).  Round 25.
// prep = R23 (swapped-MFMA vector stores, nplace=80).  sgo rebuilt around an
// EDGE-BALANCED gather: 32 groups each process an equal slice of the sorted
// edge list (kills the Poisson max-degree tail, ~65% waste at lambda=16).
// Segment tracking via s_off + binary search; per-segment register accum
// flushed into f32 LDS H via ds atomicAdd (boundary nodes sum correctly).
// P rows pre-staged in LDS; out-GEMM converts H f32->f16 on the fly.

typedef _Float16 half8 __attribute__((ext_vector_type(8)));
typedef _Float16 half4 __attribute__((ext_vector_type(4)));
typedef _Float16 half2t __attribute__((ext_vector_type(2)));
typedef float f32x4 __attribute__((ext_vector_type(4)));
typedef float f32x2 __attribute__((ext_vector_type(2)));

#define LDK 72      // pq LDS stride (halves)
#define LDW2 104    // W2^T LDS stride (halves)
#define LDP 104     // sP stride (halves; 208B, 16B-aligned rows)
#define LDHF 100    // sHf stride (dwords; 400B, 16B-aligned rows)
#define BCAP 1024   // bucket capacity (slots)
#define NBMAX 1563  // buckets for 50000 nodes @32/bucket
#define BSTRIDE 16  // bcur stride in ints (64B line per counter)

static __device__ __forceinline__ unsigned char f32_to_fp8(float v) {
    int p = __builtin_amdgcn_cvt_pk_fp8_f32(v, v, 0, false);
    return (unsigned char)(p & 0xff);
}

// ---------------- K1: prep = place (blocks 0..nplace-1) ∥ pq (rest) --------
__global__ __launch_bounds__(512) void prep_kernel(
    const float* __restrict__ x, const float* __restrict__ scalars,
    const float* __restrict__ W1, const float* __restrict__ b1,
    const float* __restrict__ W2, _Float16* __restrict__ W2T,
    _Float16* __restrict__ Pbuf, unsigned char* __restrict__ Qf8,
    const int* __restrict__ src, const int* __restrict__ dst,
    int* __restrict__ bcur, unsigned int* __restrict__ pairs,
    int tiles, int n_e4, int epb4, int nb, int nplace)
{
    __shared__ union {
        struct { int h[NBMAX]; int cur[NBMAX]; } pl;   // 12.5 KB
        _Float16 sW[192 * LDK];                        // 27.6 KB
    } sm;
    const int tid = threadIdx.x;

    if ((int)blockIdx.x < nplace) {
        // ================= place =================
        int* h = sm.pl.h;
        int* cur = sm.pl.cur;
        for (int b = tid; b < nb; b += 512) h[b] = 0;
        __syncthreads();

        const int base4 = blockIdx.x * epb4;
        for (int i = tid; i < epb4; i += 512) {          // sweep 1: count
            int i4 = base4 + i;
            if (i4 < n_e4) {
                int4 d = ((const int4*)dst)[i4];
                atomicAdd(&h[d.x >> 5], 1);
                atomicAdd(&h[d.y >> 5], 1);
                atomicAdd(&h[d.z >> 5], 1);
                atomicAdd(&h[d.w >> 5], 1);
            }
        }
        __syncthreads();
        for (int b = tid; b < nb; b += 512) {            // reserve global ranges
            int c = h[b];
            cur[b] = b * BCAP + (c ? atomicAdd(&bcur[b * BSTRIDE], c) : 0);
        }
        __syncthreads();
        for (int i = tid; i < epb4; i += 512) {          // sweep 2: place
            int i4 = base4 + i;
            if (i4 < n_e4) {
                int4 s = ((const int4*)src)[i4];
                int4 d = ((const int4*)dst)[i4];
                int p;
                p = atomicAdd(&cur[d.x >> 5], 1);
                if (p < (d.x >> 5) * BCAP + BCAP) pairs[p] = (unsigned)s.x | ((unsigned)(d.x & 31) << 16);
                p = atomicAdd(&cur[d.y >> 5], 1);
                if (p < (d.y >> 5) * BCAP + BCAP) pairs[p] = (unsigned)s.y | ((unsigned)(d.y & 31) << 16);
                p = atomicAdd(&cur[d.z >> 5], 1);
                if (p < (d.z >> 5) * BCAP + BCAP) pairs[p] = (unsigned)s.z | ((unsigned)(d.z & 31) << 16);
                p = atomicAdd(&cur[d.w >> 5], 1);
                if (p < (d.w >> 5) * BCAP + BCAP) pairs[p] = (unsigned)s.w | ((unsigned)(d.w & 31) << 16);
            }
        }
    } else {
        // ================= pq: P' = h@(W1a-W1b)+b1 (f16), Q = h@W1b (fp8) ====
        _Float16* sW = sm.sW;
        for (int idx = tid; idx < 192 * 64; idx += 512) {
            int n = idx >> 6, k = idx & 63;
            float v = 0.f;
            if (k < 48)
                v = (n < 96) ? (W1[k * 96 + n] - W1[(k + 48) * 96 + n])
                             : W1[(k + 48) * 96 + (n - 96)];
            sW[n * LDK + k] = (_Float16)v;
        }
        const int pb = blockIdx.x - nplace;
        if (pb == 0) {
            // one-time W2^T f16 pre-convert for sgo: W2T[n][k] (packed, 96/row)
            for (int idx = tid; idx < 96 * 64; idx += 512) {
                int k = idx / 64, n = idx - k * 64;      // W2 row-major [k][n]
                W2T[n * 96 + k] = (_Float16)W2[idx];
            }
        }
        __syncthreads();

        const int wave = tid >> 6, lane = tid & 63;      // wave in [0,8)
        const int quad = lane >> 4, r = lane & 15;
        const int stride = (gridDim.x - nplace) * 8;

        // bias preload: 4 consecutive cols per (nt,quad); invariant over tiles
        f32x4 bbv[6];
        #pragma unroll
        for (int nt = 0; nt < 6; ++nt)
            bbv[nt] = *(const f32x4*)&b1[nt * 16 + quad * 4];

        for (int tile = pb * 8 + wave; tile < tiles; tile += stride) {
            const int node = tile * 16 + r;

            half8 a0, a1;
            {
                const f32x4* xp = (const f32x4*)(x + (size_t)node * 32 + quad * 8);
                f32x4 v0 = xp[0], v1 = xp[1];
                #pragma unroll
                for (int j = 0; j < 4; ++j) {
                    a0[j] = (_Float16)v0[j];
                    a0[4 + j] = (_Float16)v1[j];
                }
                #pragma unroll
                for (int j = 0; j < 8; ++j) {
                    int k2 = 32 + quad * 8 + j;
                    a1[j] = (k2 < 48) ? (_Float16)scalars[k2 - 32] : (_Float16)0.f;
                }
            }

            #pragma unroll
            for (int nt = 0; nt < 12; ++nt) {
                f32x4 c = {0.f, 0.f, 0.f, 0.f};
                half8 b0 = *(const half8*)&sW[(nt * 16 + r) * LDK + quad * 8];
                half8 b1v = *(const half8*)&sW[(nt * 16 + r) * LDK + 32 + quad * 8];
                // swapped operands: lane holds 4 consecutive cols of node r
                c = __builtin_amdgcn_mfma_f32_16x16x32_f16(b0, a0, c, 0, 0, 0);
                c = __builtin_amdgcn_mfma_f32_16x16x32_f16(b1v, a1, c, 0, 0, 0);
                if (nt < 6) {
                    const int colbase = nt * 16 + quad * 4;
                    half4 pv;
                    #pragma unroll
                    for (int i = 0; i < 4; ++i)
                        pv[i] = (_Float16)(c[i] + bbv[nt][i]);
                    *(half4*)&Pbuf[(size_t)node * 96 + colbase] = pv;
                } else {
                    const int colbase = (nt - 6) * 16 + quad * 4;
                    int lo = __builtin_amdgcn_cvt_pk_fp8_f32(c[0], c[1], 0, false);
                    int full = __builtin_amdgcn_cvt_pk_fp8_f32(c[2], c[3], lo, true);
                    *(unsigned int*)&Qf8[(size_t)node * 96 + colbase] = (unsigned)full;
                }
            }
        }
    }
}

// one edge's contribution: 12 cols (lane j), fp8 Q dwords q0..q2
static __device__ __forceinline__ void acc_edge(
    float* __restrict__ ac, const float* __restrict__ pf,
    unsigned int q0, unsigned int q1, unsigned int q2)
{
    f32x2 v;
    v = __builtin_amdgcn_cvt_pk_f32_fp8((int)q0, false);
    { float t0 = pf[0] + v[0], t1 = pf[1] + v[1];
      ac[0] += t0 > 0.f ? t0 : 0.f; ac[1] += t1 > 0.f ? t1 : 0.f; }
    v = __builtin_amdgcn_cvt_pk_f32_fp8((int)q0, true);
    { float t0 = pf[2] + v[0], t1 = pf[3] + v[1];
      ac[2] += t0 > 0.f ? t0 : 0.f; ac[3] += t1 > 0.f ? t1 : 0.f; }
    v = __builtin_amdgcn_cvt_pk_f32_fp8((int)q1, false);
    { float t0 = pf[4] + v[0], t1 = pf[5] + v[1];
      ac[4] += t0 > 0.f ? t0 : 0.f; ac[5] += t1 > 0.f ? t1 : 0.f; }
    v = __builtin_amdgcn_cvt_pk_f32_fp8((int)q1, true);
    { float t0 = pf[6] + v[0], t1 = pf[7] + v[1];
      ac[6] += t0 > 0.f ? t0 : 0.f; ac[7] += t1 > 0.f ? t1 : 0.f; }
    v = __builtin_amdgcn_cvt_pk_f32_fp8((int)q2, false);
    { float t0 = pf[8] + v[0], t1 = pf[9] + v[1];
      ac[8] += t0 > 0.f ? t0 : 0.f; ac[9] += t1 > 0.f ? t1 : 0.f; }
    v = __builtin_amdgcn_cvt_pk_f32_fp8((int)q2, true);
    { float t0 = pf[10] + v[0], t1 = pf[11] + v[1];
      ac[10] += t0 > 0.f ? t0 : 0.f; ac[11] += t1 > 0.f ? t1 : 0.f; }
}

// ---------------- K2: sort + EDGE-BALANCED gather + out GEMM ----------------
__global__ __launch_bounds__(256) void sgo_kernel(
    const _Float16* __restrict__ Pbuf, const unsigned char* __restrict__ Qf8,
    const int* __restrict__ bcur, const unsigned int* __restrict__ pairs,
    const _Float16* __restrict__ W2T, const float* __restrict__ b2,
    float* __restrict__ out, int n_nodes)
{
    __shared__ unsigned short s_sorted[BCAP];   // 2 KB
    __shared__ _Float16 sW2T[64 * LDW2];        // 13.3 KB  W2^T[n][k]
    __shared__ float sHf[32 * LDHF];            // 12.8 KB  H accum (f32)
    __shared__ _Float16 sP[32 * LDP];           // 6.7 KB   P rows of bucket
    __shared__ int s_cnt[32];
    __shared__ int s_off[33];
    __shared__ int s_cur[32];

    const int b = blockIdx.x;
    const int tid = threadIdx.x;
    const int lo_g = b * BCAP;
    int cnt = bcur[b * BSTRIDE];
    if (cnt > BCAP) cnt = BCAP;   // statistically unreachable

    // stage W2^T (pre-converted f16, vectorized)
    for (int idx = tid; idx < 768; idx += 256) {
        int n = idx / 12, c = idx - n * 12;
        *(half8*)&sW2T[n * LDW2 + c * 8] = *(const half8*)&W2T[n * 96 + c * 8];
    }
    // stage this bucket's 32 P rows (f16); zero rows past n_nodes
    for (int idx = tid; idx < 384; idx += 256) {
        int n = idx / 12, c = idx - n * 12;
        int nd = b * 32 + n;
        half8 v = {};
        if (nd < n_nodes) v = *(const half8*)&Pbuf[(size_t)nd * 96 + c * 8];
        *(half8*)&sP[n * LDP + c * 8] = v;
    }
    // zero H accumulator
    for (int idx = tid; idx < 32 * LDHF; idx += 256) sHf[idx] = 0.f;

    // pairs register-cache: single global sweep
    unsigned int ureg[4];
    int nit = 0;
    for (int i = tid; i < cnt; i += 256) ureg[nit++] = pairs[lo_g + i];

    if (tid < 32) s_cnt[tid] = 0;
    __syncthreads();

    // histogram
    for (int t = 0; t < nit; ++t)
        atomicAdd(&s_cnt[(ureg[t] >> 16) & 31], 1);
    __syncthreads();
    if (tid == 0) {
        int a = 0;
        #pragma unroll
        for (int l = 0; l < 32; ++l) { s_off[l] = a; a += s_cnt[l]; }
        s_off[32] = a;
    }
    __syncthreads();
    if (tid < 32) s_cur[tid] = s_off[tid];
    __syncthreads();
    for (int t = 0; t < nit; ++t) {             // counting-sort placement
        unsigned int u = ureg[t];
        int p = atomicAdd(&s_cur[(u >> 16) & 31], 1);
        s_sorted[p] = (unsigned short)(u & 0xffffu);
    }
    __syncthreads();

    // --------- edge-balanced gather: slice gs of sorted edges -------------
    const int wave = tid >> 6, lane = tid & 63;
    const int g = lane >> 3, j = lane & 7;
    const int gs = wave * 8 + g;                // slice id 0..31

    {
        const int tot = s_off[32];
        const int lo = (gs * tot) >> 5;
        const int hi = ((gs + 1) * tot) >> 5;

        if (lo < hi) {
            // binary search: last nc in [0,31] with s_off[nc] <= lo
            int nc = 0;
            #pragma unroll
            for (int sh = 4; sh >= 0; --sh) {
                int cand = nc + (1 << sh);
                if (cand <= 31 && s_off[cand] <= lo) nc = cand;
            }
            int nend = s_off[nc + 1];

            float pf[12];
            {   // load P row nc (LDS)
                const unsigned int* Pp = (const unsigned int*)&sP[nc * LDP];
                #pragma unroll
                for (int t = 0; t < 6; ++t) {
                    half2t h = __builtin_bit_cast(half2t, Pp[j * 6 + t]);
                    pf[2 * t] = (float)h[0];
                    pf[2 * t + 1] = (float)h[1];
                }
            }

            float ac[12];
            #pragma unroll
            for (int k = 0; k < 12; ++k) ac[k] = 0.f;
            bool dirty = false;

            unsigned int A0, A1, A2;
            {
                int s0 = s_sorted[lo];
                const unsigned int* Q = (const unsigned int*)(Qf8 + (size_t)s0 * 96) + j * 3;
                A0 = Q[0]; A1 = Q[1]; A2 = Q[2];
            }
            for (int i = lo; i < hi; ++i) {
                unsigned int N0 = 0, N1 = 0, N2 = 0;
                if (i + 1 < hi) {
                    int sn = s_sorted[i + 1];
                    const unsigned int* Qn = (const unsigned int*)(Qf8 + (size_t)sn * 96) + j * 3;
                    N0 = Qn[0]; N1 = Qn[1]; N2 = Qn[2];
                }
                while (i >= nend) {             // advance segment(s)
                    if (dirty) {
                        #pragma unroll
                        for (int k = 0; k < 12; ++k) {
                            atomicAdd(&sHf[nc * LDHF + j * 12 + k], ac[k]);
                            ac[k] = 0.f;
                        }
                        dirty = false;
                    }
                    ++nc; nend = s_off[nc + 1];
                    const unsigned int* Pp = (const unsigned int*)&sP[nc * LDP];
                    #pragma unroll
                    for (int t = 0; t < 6; ++t) {
                        half2t h = __builtin_bit_cast(half2t, Pp[j * 6 + t]);
                        pf[2 * t] = (float)h[0];
                        pf[2 * t + 1] = (float)h[1];
                    }
                }
                acc_edge(ac, pf, A0, A1, A2); dirty = true;
                A0 = N0; A1 = N1; A2 = N2;
            }
            if (dirty) {
                #pragma unroll
                for (int k = 0; k < 12; ++k)
                    atomicAdd(&sHf[nc * LDHF + j * 12 + k], ac[k]);
            }
        }
    }
    __syncthreads();

    // out GEMM: tile t = wave>>1 (16 nodes), nt pair = (wave&1)*2 + {0,1}
    // A-operand converted f32->f16 on the fly from sHf.
    const int quad = lane >> 4, r = lane & 15;
    const int t = wave >> 1;
    const int nt0 = (wave & 1) * 2;

    half8 a[3];
    #pragma unroll
    for (int kk = 0; kk < 3; ++kk) {
        const float* hp = &sHf[(t * 16 + r) * LDHF + kk * 32 + quad * 8];
        f32x4 v0 = *(const f32x4*)hp;
        f32x4 v1 = *(const f32x4*)(hp + 4);
        half8 av;
        #pragma unroll
        for (int e = 0; e < 4; ++e) {
            av[e] = (_Float16)v0[e];
            av[4 + e] = (_Float16)v1[e];
        }
        a[kk] = av;
    }

    #pragma unroll
    for (int w = 0; w < 2; ++w) {
        const int nt = nt0 + w;
        f32x4 c = {0.f, 0.f, 0.f, 0.f};
        #pragma unroll
        for (int kk = 0; kk < 3; ++kk) {
            half8 bfrag = *(const half8*)&sW2T[(nt * 16 + r) * LDW2 + kk * 32 + quad * 8];
            c = __builtin_amdgcn_mfma_f32_16x16x32_f16(a[kk], bfrag, c, 0, 0, 0);
        }
        const int col = nt * 16 + r;
        const float bb = b2[col];
        #pragma unroll
        for (int i = 0; i < 4; ++i) {
            int local = t * 16 + quad * 4 + i;          // D row
            int nd = b * 32 + local;
            if (nd < n_nodes) {
                int dg = s_off[local + 1] - s_off[local];
                out[(size_t)nd * 64 + col] = c[i] + dg * bb;
            }
        }
    }
}

extern "C" void kernel_launch(void* const* d_in, const int* in_sizes, int n_in,
                              void* d_out, int out_size, void* d_ws, size_t ws_size,
                              hipStream_t stream) {
    const float* x       = (const float*)d_in[0];
    const float* scalars = (const float*)d_in[1];
    const float* W1      = (const float*)d_in[2];
    const float* b1      = (const float*)d_in[3];
    const float* W2      = (const float*)d_in[4];
    const float* b2      = (const float*)d_in[5];
    const int*   ei      = (const int*)d_in[6];
    float* out = (float*)d_out;

    const int n_edges = in_sizes[6] / 2;   // 800000
    const int n_nodes = in_sizes[0] / 32;  // 50000
    const int* src = ei;
    const int* dst = ei + n_edges;
    const int nb = (n_nodes + 31) / 32;    // 1563 buckets
    const int tiles = n_nodes / 16;        // 3125 (exact)

    // ws layout
    char* w = (char*)d_ws;
    _Float16* Pbuf = (_Float16*)w;          w += (size_t)n_nodes * 96 * 2;   // 9.6 MB
    unsigned char* Qf8 = (unsigned char*)w; w += (size_t)n_nodes * 96;       // 4.8 MB
    unsigned int* pairs = (unsigned int*)w; w += (size_t)nb * BCAP * 4;      // 6.4 MB
    _Float16* W2T = (_Float16*)w;           w += (size_t)96 * 64 * 2;        // 12.3 KB
    int* bcur = (int*)w;                    w += (size_t)nb * BSTRIDE * 4;   // 100 KB

    hipMemsetAsync(bcur, 0, (size_t)nb * BSTRIDE * 4, stream);  // zero cursors

    const int nplace = 80;                         // place blocks (of 256)
    const int n_e4 = n_edges / 4;                  // 200000
    const int epb4 = (n_e4 + nplace - 1) / nplace; // 2500
    prep_kernel<<<dim3(256), dim3(512), 0, stream>>>(
        x, scalars, W1, b1, W2, W2T, Pbuf, Qf8, src, dst, bcur, pairs,
        tiles, n_e4, epb4, nb, nplace);

    sgo_kernel<<<dim3(nb), dim3(256), 0, stream>>>(
        Pbuf, Qf8, bcur, pairs, W2T, b2, out, n_nodes);
}

// Round 18
// 118.021 us; speedup vs baseline: 1.4150x; 1.4150x over previous
//
#include <hip/hip_runtime.h>

// EFN edge-MLP + scatter-add, MI355X (gfx950).  Round 26 = R19 verbatim
// (best measured: 120.1us).  R25's edge-balanced gather regressed 1.8x on
// sgo (634K LDS bank conflicts from stride-12 f32 LDS atomics, 30% occupancy
// at 35KB LDS, serial 1-edge loop) — reverted.  Session ledger: the only
// real wins were reducing serialized same-address atomic ops (nplace 160->80,
// R18's counter-validated contention model); all latency-hiding/occupancy/
// NT/balance experiments were null or negative.

typedef _Float16 half8 __attribute__((ext_vector_type(8)));
typedef _Float16 half2t __attribute__((ext_vector_type(2)));
typedef float f32x4 __attribute__((ext_vector_type(4)));
typedef float f32x2 __attribute__((ext_vector_type(2)));

#define LDK 72      // pq LDS stride (halves)
#define LDW2 104    // W2^T LDS stride (halves)
#define LDH 104     // H LDS stride (halves); /2 = 52 dwords
#define BCAP 1024   // bucket capacity (slots)
#define NBMAX 1563  // buckets for 50000 nodes @32/bucket
#define BSTRIDE 16  // bcur stride in ints (64B line per counter)

static __device__ __forceinline__ unsigned char f32_to_fp8(float v) {
    int p = __builtin_amdgcn_cvt_pk_fp8_f32(v, v, 0, false);
    return (unsigned char)(p & 0xff);
}

// ---------------- K1: prep = place (blocks 0..nplace-1) ∥ pq (rest) --------
// 512 threads/block: place sweeps stride 512; pq runs 8 waves/block.
__global__ __launch_bounds__(512) void prep_kernel(
    const float* __restrict__ x, const float* __restrict__ scalars,
    const float* __restrict__ W1, const float* __restrict__ b1,
    const float* __restrict__ W2, _Float16* __restrict__ W2T,
    _Float16* __restrict__ Pbuf, unsigned char* __restrict__ Qf8,
    const int* __restrict__ src, const int* __restrict__ dst,
    int* __restrict__ bcur, unsigned int* __restrict__ pairs,
    int tiles, int n_e4, int epb4, int nb, int nplace)
{
    __shared__ union {
        struct { int h[NBMAX]; int cur[NBMAX]; } pl;   // 12.5 KB
        _Float16 sW[192 * LDK];                        // 27.6 KB
    } sm;
    const int tid = threadIdx.x;

    if ((int)blockIdx.x < nplace) {
        // ================= place =================
        int* h = sm.pl.h;
        int* cur = sm.pl.cur;
        for (int b = tid; b < nb; b += 512) h[b] = 0;
        __syncthreads();

        const int base4 = blockIdx.x * epb4;
        for (int i = tid; i < epb4; i += 512) {          // sweep 1: count
            int i4 = base4 + i;
            if (i4 < n_e4) {
                int4 d = ((const int4*)dst)[i4];
                atomicAdd(&h[d.x >> 5], 1);
                atomicAdd(&h[d.y >> 5], 1);
                atomicAdd(&h[d.z >> 5], 1);
                atomicAdd(&h[d.w >> 5], 1);
            }
        }
        __syncthreads();
        for (int b = tid; b < nb; b += 512) {            // reserve global ranges
            int c = h[b];
            cur[b] = b * BCAP + (c ? atomicAdd(&bcur[b * BSTRIDE], c) : 0);
        }
        __syncthreads();
        for (int i = tid; i < epb4; i += 512) {          // sweep 2: place
            int i4 = base4 + i;
            if (i4 < n_e4) {
                int4 s = ((const int4*)src)[i4];
                int4 d = ((const int4*)dst)[i4];
                int p;
                p = atomicAdd(&cur[d.x >> 5], 1);
                if (p < (d.x >> 5) * BCAP + BCAP) pairs[p] = (unsigned)s.x | ((unsigned)(d.x & 31) << 16);
                p = atomicAdd(&cur[d.y >> 5], 1);
                if (p < (d.y >> 5) * BCAP + BCAP) pairs[p] = (unsigned)s.y | ((unsigned)(d.y & 31) << 16);
                p = atomicAdd(&cur[d.z >> 5], 1);
                if (p < (d.z >> 5) * BCAP + BCAP) pairs[p] = (unsigned)s.z | ((unsigned)(d.z & 31) << 16);
                p = atomicAdd(&cur[d.w >> 5], 1);
                if (p < (d.w >> 5) * BCAP + BCAP) pairs[p] = (unsigned)s.w | ((unsigned)(d.w & 31) << 16);
            }
        }
    } else {
        // ================= pq: P' = h@(W1a-W1b)+b1 (f16), Q = h@W1b (fp8) ====
        _Float16* sW = sm.sW;
        for (int idx = tid; idx < 192 * 64; idx += 512) {
            int n = idx >> 6, k = idx & 63;
            float v = 0.f;
            if (k < 48)
                v = (n < 96) ? (W1[k * 96 + n] - W1[(k + 48) * 96 + n])
                             : W1[(k + 48) * 96 + (n - 96)];
            sW[n * LDK + k] = (_Float16)v;
        }
        const int pb = blockIdx.x - nplace;
        if (pb == 0) {
            // one-time W2^T f16 pre-convert for sgo: W2T[n][k] (packed, 96/row)
            for (int idx = tid; idx < 96 * 64; idx += 512) {
                int k = idx / 64, n = idx - k * 64;      // W2 row-major [k][n]
                W2T[n * 96 + k] = (_Float16)W2[idx];
            }
        }
        __syncthreads();

        const int wave = tid >> 6, lane = tid & 63;      // wave in [0,8)
        const int quad = lane >> 4, r = lane & 15;
        const int stride = (gridDim.x - nplace) * 8;

        for (int tile = pb * 8 + wave; tile < tiles; tile += stride) {
            const int node = tile * 16 + r;

            half8 a0, a1;
            {
                const f32x4* xp = (const f32x4*)(x + (size_t)node * 32 + quad * 8);
                f32x4 v0 = xp[0], v1 = xp[1];
                #pragma unroll
                for (int j = 0; j < 4; ++j) {
                    a0[j] = (_Float16)v0[j];
                    a0[4 + j] = (_Float16)v1[j];
                }
                #pragma unroll
                for (int j = 0; j < 8; ++j) {
                    int k2 = 32 + quad * 8 + j;
                    a1[j] = (k2 < 48) ? (_Float16)scalars[k2 - 32] : (_Float16)0.f;
                }
            }

            #pragma unroll
            for (int nt = 0; nt < 12; ++nt) {
                f32x4 c = {0.f, 0.f, 0.f, 0.f};
                half8 b0 = *(const half8*)&sW[(nt * 16 + r) * LDK + quad * 8];
                half8 b1v = *(const half8*)&sW[(nt * 16 + r) * LDK + 32 + quad * 8];
                c = __builtin_amdgcn_mfma_f32_16x16x32_f16(a0, b0, c, 0, 0, 0);
                c = __builtin_amdgcn_mfma_f32_16x16x32_f16(a1, b1v, c, 0, 0, 0);
                if (nt < 6) {
                    int col = nt * 16 + r;
                    float bb = b1[col];
                    #pragma unroll
                    for (int i = 0; i < 4; ++i)
                        Pbuf[(size_t)(tile * 16 + quad * 4 + i) * 96 + col] = (_Float16)(c[i] + bb);
                } else {
                    int col = (nt - 6) * 16 + r;
                    #pragma unroll
                    for (int i = 0; i < 4; ++i)
                        Qf8[(size_t)(tile * 16 + quad * 4 + i) * 96 + col] = f32_to_fp8(c[i]);
                }
            }
        }
    }
}

// one edge's contribution: 12 cols (lane j), fp8 Q dwords q0..q2
static __device__ __forceinline__ void acc_edge(
    float* __restrict__ ac, const float* __restrict__ pf,
    unsigned int q0, unsigned int q1, unsigned int q2)
{
    f32x2 v;
    v = __builtin_amdgcn_cvt_pk_f32_fp8((int)q0, false);
    { float t0 = pf[0] + v[0], t1 = pf[1] + v[1];
      ac[0] += t0 > 0.f ? t0 : 0.f; ac[1] += t1 > 0.f ? t1 : 0.f; }
    v = __builtin_amdgcn_cvt_pk_f32_fp8((int)q0, true);
    { float t0 = pf[2] + v[0], t1 = pf[3] + v[1];
      ac[2] += t0 > 0.f ? t0 : 0.f; ac[3] += t1 > 0.f ? t1 : 0.f; }
    v = __builtin_amdgcn_cvt_pk_f32_fp8((int)q1, false);
    { float t0 = pf[4] + v[0], t1 = pf[5] + v[1];
      ac[4] += t0 > 0.f ? t0 : 0.f; ac[5] += t1 > 0.f ? t1 : 0.f; }
    v = __builtin_amdgcn_cvt_pk_f32_fp8((int)q1, true);
    { float t0 = pf[6] + v[0], t1 = pf[7] + v[1];
      ac[6] += t0 > 0.f ? t0 : 0.f; ac[7] += t1 > 0.f ? t1 : 0.f; }
    v = __builtin_amdgcn_cvt_pk_f32_fp8((int)q2, false);
    { float t0 = pf[8] + v[0], t1 = pf[9] + v[1];
      ac[8] += t0 > 0.f ? t0 : 0.f; ac[9] += t1 > 0.f ? t1 : 0.f; }
    v = __builtin_amdgcn_cvt_pk_f32_fp8((int)q2, true);
    { float t0 = pf[10] + v[0], t1 = pf[11] + v[1];
      ac[10] += t0 > 0.f ? t0 : 0.f; ac[11] += t1 > 0.f ? t1 : 0.f; }
}

// ---------------- K2: per-bucket LDS counting sort + gather + out GEMM ------
__global__ __launch_bounds__(256) void sgo_kernel(
    const _Float16* __restrict__ Pbuf, const unsigned char* __restrict__ Qf8,
    const int* __restrict__ bcur, const unsigned int* __restrict__ pairs,
    const _Float16* __restrict__ W2T, const float* __restrict__ b2,
    float* __restrict__ out, int n_nodes)
{
    __shared__ unsigned short s_sorted[BCAP];   // 2 KB
    __shared__ _Float16 sW2T[64 * LDW2];        // 13.3 KB  W2^T[n][k]
    __shared__ _Float16 sH[32 * LDH];           // 6.7 KB   H[local][col]
    __shared__ int s_cnt[32];
    __shared__ int s_off[33];
    __shared__ int s_cur[32];

    const int b = blockIdx.x;
    const int tid = threadIdx.x;
    const int lo_g = b * BCAP;
    int cnt = bcur[b * BSTRIDE];
    if (cnt > BCAP) cnt = BCAP;   // statistically unreachable

    // --- early register prefetches: none of these depend on the sort -------
    // W2^T: 768 half8 chunks, exactly 3 per thread; ds_write deferred.
    half8 w2r[3];
    #pragma unroll
    for (int t = 0; t < 3; ++t) {
        int idx = tid + t * 256;
        int n = idx / 12, c = idx - n * 12;
        w2r[t] = *(const half8*)&W2T[n * 96 + c * 8];
    }

    // gather geometry (needed for P prefetch)
    const int wave = tid >> 6, lane = tid & 63;
    const int g = lane >> 3, j = lane & 7;
    const int ni = wave * 8 + g;
    const int node = b * 32 + ni;

    // P-row prefetch (12 cols f16 per lane), depends only on blockIdx
    float pf[12];
    if (node < n_nodes) {
        const unsigned int* Pp = (const unsigned int*)(Pbuf + (size_t)node * 96);
        #pragma unroll
        for (int t = 0; t < 6; ++t) {
            half2t h = __builtin_bit_cast(half2t, Pp[j * 6 + t]);
            pf[2 * t] = (float)h[0];
            pf[2 * t + 1] = (float)h[1];
        }
    }

    // pairs register-cache: single global sweep, reused for histogram+placement
    unsigned int ureg[4];
    int nit = 0;
    for (int i = tid; i < cnt; i += 256) ureg[nit++] = pairs[lo_g + i];

    if (tid < 32) s_cnt[tid] = 0;
    __syncthreads();

    // histogram
    for (int t = 0; t < nit; ++t)
        atomicAdd(&s_cnt[(ureg[t] >> 16) & 31], 1);
    __syncthreads();
    if (tid == 0) {
        int a = 0;
        #pragma unroll
        for (int l = 0; l < 32; ++l) { s_off[l] = a; a += s_cnt[l]; }
        s_off[32] = a;
    }
    __syncthreads();
    if (tid < 32) s_cur[tid] = s_off[tid];
    __syncthreads();
    for (int t = 0; t < nit; ++t) {             // counting-sort placement
        unsigned int u = ureg[t];
        int p = atomicAdd(&s_cur[(u >> 16) & 31], 1);
        s_sorted[p] = (unsigned short)(u & 0xffffu);
    }
    __syncthreads();

    // W2^T stage now (data already in regs; writes drain before pre-GEMM bar)
    #pragma unroll
    for (int t = 0; t < 3; ++t) {
        int idx = tid + t * 256;
        int n = idx / 12, c = idx - n * 12;
        *(half8*)&sW2T[n * LDW2 + c * 8] = w2r[t];
    }

    // gather: group = node.  8 groups/wave x 4 waves = 32 nodes, one pass.
    // lane j covers cols j*12..j*12+11.  Software-pipelined: prefetch pair
    // (i+2,i+3) while accumulating (i,i+1); 12 dwords in flight per group.
    if (node < n_nodes) {
        const int lo = s_off[ni], hi = s_off[ni + 1];

        float ac[12];
        #pragma unroll
        for (int k = 0; k < 12; ++k) ac[k] = 0.f;

        if (lo < hi) {
            const int last = hi - 1;
            unsigned int A0, A1, A2, B0, B1, B2;
            {
                int s0 = s_sorted[lo];
                int i1 = lo + 1 <= last ? lo + 1 : last;
                int s1 = s_sorted[i1];
                const unsigned int* Q0 = (const unsigned int*)(Qf8 + (size_t)s0 * 96) + j * 3;
                const unsigned int* Q1 = (const unsigned int*)(Qf8 + (size_t)s1 * 96) + j * 3;
                A0 = Q0[0]; A1 = Q0[1]; A2 = Q0[2];
                B0 = Q1[0]; B1 = Q1[1]; B2 = Q1[2];
            }
            for (int i = lo; i < hi; i += 2) {
                int i2 = i + 2 <= last ? i + 2 : last;
                int i3 = i + 3 <= last ? i + 3 : last;
                int s2 = s_sorted[i2], s3 = s_sorted[i3];
                const unsigned int* Q2 = (const unsigned int*)(Qf8 + (size_t)s2 * 96) + j * 3;
                const unsigned int* Q3 = (const unsigned int*)(Qf8 + (size_t)s3 * 96) + j * 3;
                unsigned int NA0 = Q2[0], NA1 = Q2[1], NA2 = Q2[2];
                unsigned int NB0 = Q3[0], NB1 = Q3[1], NB2 = Q3[2];
                acc_edge(ac, pf, A0, A1, A2);
                if (i + 1 < hi) acc_edge(ac, pf, B0, B1, B2);
                A0 = NA0; A1 = NA1; A2 = NA2;
                B0 = NB0; B1 = NB1; B2 = NB2;
            }
        }

        // write H row directly (lane j owns dwords j*6..j*6+5 of the row)
        unsigned int* Hp = (unsigned int*)sH + ni * (LDH / 2);
        #pragma unroll
        for (int t = 0; t < 6; ++t) {
            half2t hv;
            hv[0] = (_Float16)ac[2 * t];
            hv[1] = (_Float16)ac[2 * t + 1];
            Hp[j * 6 + t] = __builtin_bit_cast(unsigned int, hv);
        }
    }
    __syncthreads();

    // out GEMM: tile t = wave>>1 (16 nodes), nt pair = (wave&1)*2 + {0,1}
    const int quad = lane >> 4, r = lane & 15;
    const int t = wave >> 1;
    const int nt0 = (wave & 1) * 2;

    half8 a[3];
    #pragma unroll
    for (int kk = 0; kk < 3; ++kk)
        a[kk] = *(const half8*)&sH[(t * 16 + r) * LDH + kk * 32 + quad * 8];

    #pragma unroll
    for (int w = 0; w < 2; ++w) {
        const int nt = nt0 + w;
        f32x4 c = {0.f, 0.f, 0.f, 0.f};
        #pragma unroll
        for (int kk = 0; kk < 3; ++kk) {
            half8 bfrag = *(const half8*)&sW2T[(nt * 16 + r) * LDW2 + kk * 32 + quad * 8];
            c = __builtin_amdgcn_mfma_f32_16x16x32_f16(a[kk], bfrag, c, 0, 0, 0);
        }
        const int col = nt * 16 + r;
        const float bb = b2[col];
        #pragma unroll
        for (int i = 0; i < 4; ++i) {
            int local = t * 16 + quad * 4 + i;          // D row
            int nd = b * 32 + local;
            if (nd < n_nodes) {
                int dg = s_off[local + 1] - s_off[local];
                out[(size_t)nd * 64 + col] = c[i] + dg * bb;
            }
        }
    }
}

extern "C" void kernel_launch(void* const* d_in, const int* in_sizes, int n_in,
                              void* d_out, int out_size, void* d_ws, size_t ws_size,
                              hipStream_t stream) {
    const float* x       = (const float*)d_in[0];
    const float* scalars = (const float*)d_in[1];
    const float* W1      = (const float*)d_in[2];
    const float* b1      = (const float*)d_in[3];
    const float* W2      = (const float*)d_in[4];
    const float* b2      = (const float*)d_in[5];
    const int*   ei      = (const int*)d_in[6];
    float* out = (float*)d_out;

    const int n_edges = in_sizes[6] / 2;   // 800000
    const int n_nodes = in_sizes[0] / 32;  // 50000
    const int* src = ei;
    const int* dst = ei + n_edges;
    const int nb = (n_nodes + 31) / 32;    // 1563 buckets
    const int tiles = n_nodes / 16;        // 3125 (exact)

    // ws layout
    char* w = (char*)d_ws;
    _Float16* Pbuf = (_Float16*)w;          w += (size_t)n_nodes * 96 * 2;   // 9.6 MB
    unsigned char* Qf8 = (unsigned char*)w; w += (size_t)n_nodes * 96;       // 4.8 MB
    unsigned int* pairs = (unsigned int*)w; w += (size_t)nb * BCAP * 4;      // 6.4 MB
    _Float16* W2T = (_Float16*)w;           w += (size_t)96 * 64 * 2;        // 12.3 KB
    int* bcur = (int*)w;                    w += (size_t)nb * BSTRIDE * 4;   // 100 KB

    hipMemsetAsync(bcur, 0, (size_t)nb * BSTRIDE * 4, stream);  // zero cursors

    const int nplace = 80;                         // place blocks (of 256)
    const int n_e4 = n_edges / 4;                  // 200000
    const int epb4 = (n_e4 + nplace - 1) / nplace; // 2500
    prep_kernel<<<dim3(256), dim3(512), 0, stream>>>(
        x, scalars, W1, b1, W2, W2T, Pbuf, Qf8, src, dst, bcur, pairs,
        tiles, n_e4, epb4, nb, nplace);

    sgo_kernel<<<dim3(nb), dim3(256), 0, stream>>>(
        Pbuf, Qf8, bcur, pairs, W2T, b2, out, n_nodes);
}